// Round 4
// baseline (1339.529 us; speedup 1.0000x reference)
//
#include <hip/hip_runtime.h>

// GNN NodeModel, round 4: kill the per-edge index-load chain.
// R1: 102M global f32 atomics = wall (645 us). R2: serial per-node walk =
// latency-bound (980 us). R3: edge-parallel LDS-acc, but every iteration
// gated by a wave-uniform sorted8[idx] load (650 us, VALU 20%).
// R4: lane-parallel chunk load of 64 edge records + __shfl broadcast
// (register-only index delivery -> gathers pipeline freely), A1 staged in
// LDS per block, A2 as per-lane coalesced float, NPB=32 for full occupancy.

constexpr int kNodes  = 100000;
constexpr int kEdges  = 1600000;
constexpr int kGraphs = 64;
constexpr int kD      = 32;
constexpr int kOut    = 64;
constexpr int SB      = 256;
constexpr int NB      = (kNodes + SB - 1) / SB;  // 391 scan blocks
constexpr int NPB     = 32;                      // nodes per agg block
constexpr int NAB     = kNodes / NPB;            // 3125 (exact)
static_assert(kNodes % NPB == 0, "exact node partition");
static_assert(NB <= 512, "scan_top handles <=512 block sums");

// ---------------------------------------------------------------------------
__global__ __launch_bounds__(256) void tables_kernel(
    const float* __restrict__ u, const float* __restrict__ W1,
    const float* __restrict__ b1, const float* __restrict__ W2,
    const float* __restrict__ b2, float* __restrict__ U1,
    float* __restrict__ U2) {
  int t = blockIdx.x * 256 + threadIdx.x;
  if (t >= kGraphs * kOut) return;
  int g = t >> 6, j = t & 63;
  float a1 = b1[j], a2 = b2[j];
#pragma unroll
  for (int k = 0; k < kD; ++k) {
    float uv = u[g * kD + k];
    a1 = fmaf(uv, W1[(96 + k) * kOut + j], a1);
    a2 = fmaf(uv, W2[(96 + k) * kOut + j], a2);
  }
  U1[t] = a1;
  U2[t] = a2;
}

// ---------------------------------------------------------------------------
// A1 = x @ W1[0:32], A2 = x @ W1[32:64]. One wave per node, lane = out col.
__global__ __launch_bounds__(256) void pre_kernel(
    const float* __restrict__ x, const float* __restrict__ W1,
    float* __restrict__ A1, float* __restrict__ A2) {
  __shared__ float sWa[kD * kOut];
  __shared__ float sWb[kD * kOut];
  for (int i = threadIdx.x; i < kD * kOut; i += 256) {
    sWa[i] = W1[i];
    sWb[i] = W1[kD * kOut + i];
  }
  __syncthreads();
  const int lane = threadIdx.x & 63;
  const int wave = (blockIdx.x * 256 + threadIdx.x) >> 6;
  const int nw   = gridDim.x * 4;
  for (int n = wave; n < kNodes; n += nw) {
    const float4* xr = reinterpret_cast<const float4*>(x + (size_t)n * kD);
    float a1 = 0.f, a2 = 0.f;
#pragma unroll
    for (int q = 0; q < 8; ++q) {
      float4 v = xr[q];
      int k = q * 4;
      a1 = fmaf(v.x, sWa[(k + 0) * kOut + lane], a1);
      a1 = fmaf(v.y, sWa[(k + 1) * kOut + lane], a1);
      a1 = fmaf(v.z, sWa[(k + 2) * kOut + lane], a1);
      a1 = fmaf(v.w, sWa[(k + 3) * kOut + lane], a1);
      a2 = fmaf(v.x, sWb[(k + 0) * kOut + lane], a2);
      a2 = fmaf(v.y, sWb[(k + 1) * kOut + lane], a2);
      a2 = fmaf(v.z, sWb[(k + 2) * kOut + lane], a2);
      a2 = fmaf(v.w, sWb[(k + 3) * kOut + lane], a2);
    }
    A1[(size_t)n * kOut + lane] = a1;
    A2[(size_t)n * kOut + lane] = a2;
  }
}

// ---------------------------------------------------------------------------
__global__ __launch_bounds__(256) void hist_kernel(const int* __restrict__ ei,
                                                   int* __restrict__ counts) {
  int i = blockIdx.x * 256 + threadIdx.x;
  int stride = gridDim.x * 256;
  for (int e = i; e < kEdges; e += stride)
    atomicAdd(&counts[ei[kEdges + e]], 1);
}

__global__ __launch_bounds__(SB) void scan_reduce(const int* __restrict__ counts,
                                                  int* __restrict__ bsum) {
  __shared__ int s[SB];
  int i = blockIdx.x * SB + threadIdx.x;
  s[threadIdx.x] = (i < kNodes) ? counts[i] : 0;
  __syncthreads();
  for (int off = SB / 2; off > 0; off >>= 1) {
    if (threadIdx.x < off) s[threadIdx.x] += s[threadIdx.x + off];
    __syncthreads();
  }
  if (threadIdx.x == 0) bsum[blockIdx.x] = s[0];
}

__global__ __launch_bounds__(512) void scan_top(int* __restrict__ bsum) {
  __shared__ int s[512];
  int t = threadIdx.x;
  int orig = (t < NB) ? bsum[t] : 0;
  s[t] = orig;
  __syncthreads();
  for (int off = 1; off < 512; off <<= 1) {
    int a = (t >= off) ? s[t - off] : 0;
    __syncthreads();
    s[t] += a;
    __syncthreads();
  }
  if (t < NB) bsum[t] = s[t] - orig;  // exclusive
}

__global__ __launch_bounds__(SB) void scan_final(
    const int* __restrict__ counts, const int* __restrict__ bscan,
    int* __restrict__ offs, int* __restrict__ cursor) {
  __shared__ int s[SB];
  int i = blockIdx.x * SB + threadIdx.x;
  int v = (i < kNodes) ? counts[i] : 0;
  s[threadIdx.x] = v;
  __syncthreads();
  for (int off = 1; off < SB; off <<= 1) {
    int a = (threadIdx.x >= off) ? s[threadIdx.x - off] : 0;
    __syncthreads();
    s[threadIdx.x] += a;
    __syncthreads();
  }
  if (i < kNodes) {
    int ex = s[threadIdx.x] - v + bscan[blockIdx.x];
    offs[i] = ex;
    cursor[i] = ex;
  }
  if (blockIdx.x == 0 && threadIdx.x == 0) offs[kNodes] = kEdges;
}

// Pack (e, s, g, d) into 61 bits: e<2^21, s<2^17, g<2^6, d<2^17.
__global__ __launch_bounds__(256) void scatter_kernel(
    const int* __restrict__ ei, const int* __restrict__ batch,
    int* __restrict__ cursor, unsigned long long* __restrict__ sorted8) {
  int i = blockIdx.x * 256 + threadIdx.x;
  int stride = gridDim.x * 256;
  for (int e = i; e < kEdges; e += stride) {
    int s = ei[e];
    int d = ei[kEdges + e];
    int g = batch[s];
    int pos = atomicAdd(&cursor[d], 1);
    unsigned long long v = (unsigned long long)e |
                           ((unsigned long long)s << 21) |
                           ((unsigned long long)g << 38) |
                           ((unsigned long long)d << 44);
    sorted8[pos] = v;
  }
}

// ---------------------------------------------------------------------------
// Block owns NPB dest-sorted nodes. Per 64-edge chunk: one coalesced
// lane-parallel load of the packed records, then __shfl broadcast per edge —
// no memory op on the index critical path. A1 staged in LDS; A2 is a per-lane
// coalesced float; accumulate via ds_add; plain coalesced store.
__global__ __launch_bounds__(256) void agg3_kernel(
    const unsigned long long* __restrict__ sorted8,
    const int* __restrict__ offs, const float* __restrict__ ea,
    const float* __restrict__ A1, const float* __restrict__ A2,
    const float* __restrict__ U1, const float* __restrict__ W1,
    float* __restrict__ agg) {
  __shared__ float acc[NPB * kOut];  // 8 KB
  __shared__ float a1s[NPB * kOut];  // 8 KB
  const int tid  = threadIdx.x;
  const int lane = tid & 63;
  const int wv   = tid >> 6;  // 0..3
  const int n0   = blockIdx.x * NPB;
  float wreg[kD];
#pragma unroll
  for (int k = 0; k < kD; ++k)
    wreg[k] = W1[(size_t)(2 * kD + k) * kOut + lane];
  {  // stage A1 rows, zero acc
    const float4* a1g = reinterpret_cast<const float4*>(A1 + (size_t)n0 * kOut);
    float4* a1v = reinterpret_cast<float4*>(a1s);
    for (int i = tid; i < NPB * kOut / 4; i += 256) a1v[i] = a1g[i];
    for (int i = tid; i < NPB * kOut; i += 256) acc[i] = 0.f;
  }
  __syncthreads();
  const int ebeg = offs[n0], eend = offs[n0 + NPB];
  for (int cb = ebeg + 64 * wv; cb < eend; cb += 256) {
    const int cnt = min(64, eend - cb);
    unsigned long long myrec = (lane < cnt) ? sorted8[cb + lane] : 0ull;
#pragma unroll 2
    for (int j = 0; j < cnt; ++j) {
      const unsigned long long v = __shfl(myrec, j);
      const int e  = (int)(v & 0x1FFFFFull);
      const int s  = (int)((v >> 21) & 0x1FFFFull);
      const int g  = (int)((v >> 38) & 0x3Full);
      const int dl = (int)((v >> 44) & 31ull);
      float m0 = a1s[dl * kOut + lane] + U1[g * kOut + lane];
      float m1 = A2[(size_t)s * kOut + lane];
      const float4* er = reinterpret_cast<const float4*>(ea + (size_t)e * kD);
#pragma unroll
      for (int q = 0; q < 8; ++q) {
        float4 vv = er[q];
        m0 = fmaf(vv.x, wreg[4 * q + 0], m0);
        m1 = fmaf(vv.y, wreg[4 * q + 1], m1);
        m0 = fmaf(vv.z, wreg[4 * q + 2], m0);
        m1 = fmaf(vv.w, wreg[4 * q + 3], m1);
      }
      unsafeAtomicAdd(&acc[dl * kOut + lane], fmaxf(m0 + m1, 0.f));
    }
  }
  __syncthreads();
  for (int r = wv; r < NPB; r += 4)
    agg[(size_t)(n0 + r) * kOut + lane] = acc[r * kOut + lane];
}

// ---------------------------------------------------------------------------
// out = relu(x @ W2[0:32] + agg @ W2[32:96] + U2[batch]). One wave per node.
__global__ __launch_bounds__(256) void mlp2_kernel(
    const float* __restrict__ x, const float* __restrict__ agg,
    const int* __restrict__ batch, const float* __restrict__ U2,
    const float* __restrict__ W2, float* __restrict__ out) {
  __shared__ float sWa[kD * kOut];    // W2 rows 0..31  (x block)
  __shared__ float sWb[kOut * kOut];  // W2 rows 32..95 (agg block)
  for (int i = threadIdx.x; i < kD * kOut; i += 256) sWa[i] = W2[i];
  for (int i = threadIdx.x; i < kOut * kOut; i += 256)
    sWb[i] = W2[kD * kOut + i];
  __syncthreads();
  const int lane = threadIdx.x & 63;
  const int wave = (blockIdx.x * 256 + threadIdx.x) >> 6;
  const int nw   = gridDim.x * 4;
  for (int n = wave; n < kNodes; n += nw) {
    const int g = batch[n];
    float acc = U2[g * kOut + lane];
    const float4* xr = reinterpret_cast<const float4*>(x + (size_t)n * kD);
#pragma unroll
    for (int q = 0; q < 8; ++q) {
      float4 v = xr[q];
      int k = q * 4;
      acc = fmaf(v.x, sWa[(k + 0) * kOut + lane], acc);
      acc = fmaf(v.y, sWa[(k + 1) * kOut + lane], acc);
      acc = fmaf(v.z, sWa[(k + 2) * kOut + lane], acc);
      acc = fmaf(v.w, sWa[(k + 3) * kOut + lane], acc);
    }
    const float4* ar = reinterpret_cast<const float4*>(agg + (size_t)n * kOut);
#pragma unroll
    for (int q = 0; q < 16; ++q) {
      float4 v = ar[q];
      int k = q * 4;
      acc = fmaf(v.x, sWb[(k + 0) * kOut + lane], acc);
      acc = fmaf(v.y, sWb[(k + 1) * kOut + lane], acc);
      acc = fmaf(v.z, sWb[(k + 2) * kOut + lane], acc);
      acc = fmaf(v.w, sWb[(k + 3) * kOut + lane], acc);
    }
    out[(size_t)n * kOut + lane] = fmaxf(acc, 0.f);
  }
}

// ---------------------------------------------------------------------------
extern "C" void kernel_launch(void* const* d_in, const int* in_sizes, int n_in,
                              void* d_out, int out_size, void* d_ws,
                              size_t ws_size, hipStream_t stream) {
  const float* x     = (const float*)d_in[0];
  const int*   ei    = (const int*)d_in[1];
  const float* ea    = (const float*)d_in[2];
  const float* u     = (const float*)d_in[3];
  const int*   batch = (const int*)d_in[4];
  const float* W1    = (const float*)d_in[5];
  const float* b1    = (const float*)d_in[6];
  const float* W2    = (const float*)d_in[7];
  const float* b2    = (const float*)d_in[8];
  float* out = (float*)d_out;

  // Workspace layout (~91 MB, proven footprint).
  float* A1 = (float*)d_ws;
  float* A2 = A1 + (size_t)kNodes * kOut;
  float* agg = A2 + (size_t)kNodes * kOut;
  unsigned long long* sorted8 =
      (unsigned long long*)(agg + (size_t)kNodes * kOut);
  float* U1   = (float*)(sorted8 + kEdges);
  float* U2   = U1 + kGraphs * kOut;
  int* counts = (int*)(U2 + kGraphs * kOut);
  int* offs   = counts + kNodes;  // kNodes+1 entries
  int* cursor = offs + kNodes + 1;
  int* bsum   = cursor + kNodes;  // NB entries

  hipMemsetAsync(counts, 0, (size_t)kNodes * sizeof(int), stream);
  tables_kernel<<<(kGraphs * kOut + 255) / 256, 256, 0, stream>>>(
      u, W1, b1, W2, b2, U1, U2);
  pre_kernel<<<1024, 256, 0, stream>>>(x, W1, A1, A2);
  hist_kernel<<<2048, 256, 0, stream>>>(ei, counts);
  scan_reduce<<<NB, SB, 0, stream>>>(counts, bsum);
  scan_top<<<1, 512, 0, stream>>>(bsum);
  scan_final<<<NB, SB, 0, stream>>>(counts, bsum, offs, cursor);
  scatter_kernel<<<2048, 256, 0, stream>>>(ei, batch, cursor, sorted8);
  agg3_kernel<<<NAB, 256, 0, stream>>>(sorted8, offs, ea, A1, A2, U1, W1, agg);
  mlp2_kernel<<<1024, 256, 0, stream>>>(x, agg, batch, U2, W2, out);
}

// Round 6
// 1178.419 us; speedup vs baseline: 1.1367x; 1.1367x over previous
//
#include <hip/hip_runtime.h>
#include <cmath>

// GNN NodeModel, round 5 resubmit (R5 bench was GPUAcquisitionTimeout; no data).
// R1: 102M global f32 atomics = wall (645 us, 1.47 TB/s sustained otherwise).
// R2-R4: ALL dest-sorted gather-side aggregations latency-bound at 650-980 us
//        (VALU 16-20%, HBM 4-6%) regardless of index delivery mechanism.
// R5: edge pass in ORIGINAL order (ea streams, R1-proven shape): ballot-scan
//     64 edges/wave, 1 int atomic/edge for its dest-sorted slot, message rows
//     stored scattered-but-full-line (256 B) to msgbuf. Then a pure-streaming
//     segment-sum fused with MLP2. No f32 atomics, no 8B scattered RMW writes.
//     msgbuf sized from ws_size; dest-range passes (P) cover any ws >= ~66 MB.

constexpr int kNodes  = 100000;
constexpr int kEdges  = 1600000;
constexpr int kGraphs = 64;
constexpr int kD      = 32;
constexpr int kOut    = 64;
constexpr int SB      = 256;
constexpr int NB      = (kNodes + SB - 1) / SB;  // 391 scan blocks
static_assert(NB <= 512, "scan_top handles <=512 block sums");

// ---------------------------------------------------------------------------
__global__ __launch_bounds__(256) void tables_kernel(
    const float* __restrict__ u, const float* __restrict__ W1,
    const float* __restrict__ b1, const float* __restrict__ W2,
    const float* __restrict__ b2, float* __restrict__ U1,
    float* __restrict__ U2) {
  int t = blockIdx.x * 256 + threadIdx.x;
  if (t >= kGraphs * kOut) return;
  int g = t >> 6, j = t & 63;
  float a1 = b1[j], a2 = b2[j];
#pragma unroll
  for (int k = 0; k < kD; ++k) {
    float uv = u[g * kD + k];
    a1 = fmaf(uv, W1[(96 + k) * kOut + j], a1);
    a2 = fmaf(uv, W2[(96 + k) * kOut + j], a2);
  }
  U1[t] = a1;
  U2[t] = a2;
}

// ---------------------------------------------------------------------------
// A1 = x @ W1[0:32], A2 = x @ W1[32:64]. One wave per node, lane = out col.
__global__ __launch_bounds__(256) void pre_kernel(
    const float* __restrict__ x, const float* __restrict__ W1,
    float* __restrict__ A1, float* __restrict__ A2) {
  __shared__ float sWa[kD * kOut];
  __shared__ float sWb[kD * kOut];
  for (int i = threadIdx.x; i < kD * kOut; i += 256) {
    sWa[i] = W1[i];
    sWb[i] = W1[kD * kOut + i];
  }
  __syncthreads();
  const int lane = threadIdx.x & 63;
  const int wave = (blockIdx.x * 256 + threadIdx.x) >> 6;
  const int nw   = gridDim.x * 4;
  for (int n = wave; n < kNodes; n += nw) {
    const float4* xr = reinterpret_cast<const float4*>(x + (size_t)n * kD);
    float a1 = 0.f, a2 = 0.f;
#pragma unroll
    for (int q = 0; q < 8; ++q) {
      float4 v = xr[q];
      int k = q * 4;
      a1 = fmaf(v.x, sWa[(k + 0) * kOut + lane], a1);
      a1 = fmaf(v.y, sWa[(k + 1) * kOut + lane], a1);
      a1 = fmaf(v.z, sWa[(k + 2) * kOut + lane], a1);
      a1 = fmaf(v.w, sWa[(k + 3) * kOut + lane], a1);
      a2 = fmaf(v.x, sWb[(k + 0) * kOut + lane], a2);
      a2 = fmaf(v.y, sWb[(k + 1) * kOut + lane], a2);
      a2 = fmaf(v.z, sWb[(k + 2) * kOut + lane], a2);
      a2 = fmaf(v.w, sWb[(k + 3) * kOut + lane], a2);
    }
    A1[(size_t)n * kOut + lane] = a1;
    A2[(size_t)n * kOut + lane] = a2;
  }
}

// ---------------------------------------------------------------------------
__global__ __launch_bounds__(256) void hist_kernel(const int* __restrict__ ei,
                                                   int* __restrict__ counts) {
  int i = blockIdx.x * 256 + threadIdx.x;
  int stride = gridDim.x * 256;
  for (int e = i; e < kEdges; e += stride)
    atomicAdd(&counts[ei[kEdges + e]], 1);
}

__global__ __launch_bounds__(SB) void scan_reduce(const int* __restrict__ counts,
                                                  int* __restrict__ bsum) {
  __shared__ int s[SB];
  int i = blockIdx.x * SB + threadIdx.x;
  s[threadIdx.x] = (i < kNodes) ? counts[i] : 0;
  __syncthreads();
  for (int off = SB / 2; off > 0; off >>= 1) {
    if (threadIdx.x < off) s[threadIdx.x] += s[threadIdx.x + off];
    __syncthreads();
  }
  if (threadIdx.x == 0) bsum[blockIdx.x] = s[0];
}

__global__ __launch_bounds__(512) void scan_top(int* __restrict__ bsum) {
  __shared__ int s[512];
  int t = threadIdx.x;
  int orig = (t < NB) ? bsum[t] : 0;
  s[t] = orig;
  __syncthreads();
  for (int off = 1; off < 512; off <<= 1) {
    int a = (t >= off) ? s[t - off] : 0;
    __syncthreads();
    s[t] += a;
    __syncthreads();
  }
  if (t < NB) bsum[t] = s[t] - orig;  // exclusive
}

__global__ __launch_bounds__(SB) void scan_final(
    const int* __restrict__ counts, const int* __restrict__ bscan,
    int* __restrict__ offs, int* __restrict__ cursor) {
  __shared__ int s[SB];
  int i = blockIdx.x * SB + threadIdx.x;
  int v = (i < kNodes) ? counts[i] : 0;
  s[threadIdx.x] = v;
  __syncthreads();
  for (int off = 1; off < SB; off <<= 1) {
    int a = (threadIdx.x >= off) ? s[threadIdx.x - off] : 0;
    __syncthreads();
    s[threadIdx.x] += a;
    __syncthreads();
  }
  if (i < kNodes) {
    int ex = s[threadIdx.x] - v + bscan[blockIdx.x];
    offs[i] = ex;
    cursor[i] = ex;
  }
  if (blockIdx.x == 0 && threadIdx.x == 0) offs[kNodes] = kEdges;
}

// ---------------------------------------------------------------------------
// Edge pass for dests in [dlo, dhi). Original edge order: 64 edges scanned
// per wave (coalesced index loads + ballot). Matching edges: 1 int atomic for
// the dest-sorted slot, per-lane record packed to LDS, then per edge one
// uniform ds_read_b128 delivers indices; message computed by all 64 lanes
// (lane = out col) and stored as a full 256 B row to msgbuf. Scattered but
// full-line writes: no RMW, no f32 atomics. Only LDS traffic = rec ops.
__global__ __launch_bounds__(256) void edge_msg_kernel(
    const int* __restrict__ ei, const int* __restrict__ batch,
    const float* __restrict__ ea, const float* __restrict__ A1,
    const float* __restrict__ A2, const float* __restrict__ U1,
    const float* __restrict__ W1, const int* __restrict__ offs,
    int* __restrict__ cursor, float* __restrict__ msgbuf, int dlo, int dhi) {
  __shared__ uint4 rec[4][64];  // 4 KB
  const int tid  = threadIdx.x;
  const int lane = tid & 63;
  const int wv   = tid >> 6;
  float wreg[kD];
#pragma unroll
  for (int k = 0; k < kD; ++k)
    wreg[k] = W1[(size_t)(2 * kD + k) * kOut + lane];
  const int base   = offs[dlo];
  const int waveId = (blockIdx.x * 256 + tid) >> 6;
  const int nWaves = gridDim.x * 4;
  for (long long c0 = (long long)waveId * 64; c0 < kEdges;
       c0 += (long long)nWaves * 64) {
    const int et = (int)c0 + lane;
    int s = 0, d = -1;
    if (et < kEdges) {
      s = ei[et];
      d = ei[kEdges + et];
    }
    const bool m = (d >= dlo) && (d < dhi);
    unsigned long long bal = __ballot(m);
    if (!bal) continue;
    int g = 0, pos = 0;
    if (m) {
      g   = batch[s];
      pos = atomicAdd(&cursor[d], 1) - base;
    }
    rec[wv][lane] = make_uint4((unsigned)et, (unsigned)s,
                               (unsigned)(d - dlo) | ((unsigned)g << 20),
                               (unsigned)pos);
    while (bal) {
      const int j = __ffsll(bal) - 1;
      bal &= bal - 1;
      const uint4 r = rec[wv][j];
      const int e2 = (int)r.x, s2 = (int)r.y;
      const int dl = (int)(r.z & 0xFFFFFu), g2 = (int)(r.z >> 20);
      const int p2 = (int)r.w;
      float m0 = A1[(size_t)(dlo + dl) * kOut + lane] + U1[g2 * kOut + lane];
      float m1 = A2[(size_t)s2 * kOut + lane];
      const float4* er = reinterpret_cast<const float4*>(ea + (size_t)e2 * kD);
#pragma unroll
      for (int q = 0; q < 8; ++q) {
        float4 v = er[q];
        m0 = fmaf(v.x, wreg[4 * q + 0], m0);
        m1 = fmaf(v.y, wreg[4 * q + 1], m1);
        m0 = fmaf(v.z, wreg[4 * q + 2], m0);
        m1 = fmaf(v.w, wreg[4 * q + 3], m1);
      }
      msgbuf[(size_t)p2 * kOut + lane] = fmaxf(m0 + m1, 0.f);
    }
  }
}

// ---------------------------------------------------------------------------
// Fused segment-sum + MLP2 for nodes [nlo, nhi). Per node: sum contiguous
// msgbuf rows (pure sequential stream), LDS roundtrip the agg row, then
// out = relu(x @ W2[0:32] + agg @ W2[32:96] + U2[batch]).
__global__ __launch_bounds__(256) void sum_mlp2_kernel(
    const float* __restrict__ x, const float* __restrict__ msgbuf,
    const int* __restrict__ offs, const int* __restrict__ batch,
    const float* __restrict__ U2, const float* __restrict__ W2,
    float* __restrict__ out, int nlo, int nhi) {
  __shared__ float sWa[kD * kOut];    // W2 rows 0..31  (x block)
  __shared__ float sWb[kOut * kOut];  // W2 rows 32..95 (agg block)
  __shared__ float aggrow[4 * kOut];
  for (int i = threadIdx.x; i < kD * kOut; i += 256) sWa[i] = W2[i];
  for (int i = threadIdx.x; i < kOut * kOut; i += 256)
    sWb[i] = W2[kD * kOut + i];
  __syncthreads();
  const int lane = threadIdx.x & 63;
  const int wv   = threadIdx.x >> 6;
  const int base = offs[nlo];
  const int wave = (blockIdx.x * 256 + threadIdx.x) >> 6;
  const int nw   = gridDim.x * 4;
  for (int n = nlo + wave; n < nhi; n += nw) {
    const int rb = offs[n] - base, re = offs[n + 1] - base;
    float a0 = 0.f, a1 = 0.f;
    int r = rb;
    for (; r + 1 < re; r += 2) {
      a0 += msgbuf[(size_t)r * kOut + lane];
      a1 += msgbuf[(size_t)(r + 1) * kOut + lane];
    }
    if (r < re) a0 += msgbuf[(size_t)r * kOut + lane];
    aggrow[wv * kOut + lane] = a0 + a1;
    float acc = U2[batch[n] * kOut + lane];
    const float4* xr = reinterpret_cast<const float4*>(x + (size_t)n * kD);
#pragma unroll
    for (int q = 0; q < 8; ++q) {
      float4 v = xr[q];
      int k = q * 4;
      acc = fmaf(v.x, sWa[(k + 0) * kOut + lane], acc);
      acc = fmaf(v.y, sWa[(k + 1) * kOut + lane], acc);
      acc = fmaf(v.z, sWa[(k + 2) * kOut + lane], acc);
      acc = fmaf(v.w, sWa[(k + 3) * kOut + lane], acc);
    }
#pragma unroll
    for (int q = 0; q < 16; ++q) {
      float4 v = *reinterpret_cast<const float4*>(&aggrow[wv * kOut + q * 4]);
      int k = q * 4;
      acc = fmaf(v.x, sWb[(k + 0) * kOut + lane], acc);
      acc = fmaf(v.y, sWb[(k + 1) * kOut + lane], acc);
      acc = fmaf(v.z, sWb[(k + 2) * kOut + lane], acc);
      acc = fmaf(v.w, sWb[(k + 3) * kOut + lane], acc);
    }
    out[(size_t)n * kOut + lane] = fmaxf(acc, 0.f);
  }
}

// ---------------------------------------------------------------------------
extern "C" void kernel_launch(void* const* d_in, const int* in_sizes, int n_in,
                              void* d_out, int out_size, void* d_ws,
                              size_t ws_size, hipStream_t stream) {
  const float* x     = (const float*)d_in[0];
  const int*   ei    = (const int*)d_in[1];
  const float* ea    = (const float*)d_in[2];
  const float* u     = (const float*)d_in[3];
  const int*   batch = (const int*)d_in[4];
  const float* W1    = (const float*)d_in[5];
  const float* b1    = (const float*)d_in[6];
  const float* W2    = (const float*)d_in[7];
  const float* b2    = (const float*)d_in[8];
  float* out = (float*)d_out;

  // Fixed workspace: A1, A2, U1, U2, counts, offs, cursor, bsum (~52.4 MB).
  float* A1   = (float*)d_ws;
  float* A2   = A1 + (size_t)kNodes * kOut;
  float* U1   = A2 + (size_t)kNodes * kOut;
  float* U2   = U1 + kGraphs * kOut;
  int* counts = (int*)(U2 + kGraphs * kOut);
  int* offs   = counts + kNodes;  // kNodes+1 entries
  int* cursor = offs + kNodes + 1;
  int* bsum   = cursor + kNodes;  // NB entries
  char* endp  = (char*)(bsum + NB);
  size_t fixed = (size_t)(endp - (char*)d_ws);
  fixed = (fixed + 255) & ~(size_t)255;
  float* msgbuf = (float*)((char*)d_ws + fixed);

  // Pick pass count P so the largest dest-range pass fits msgbuf capacity.
  size_t capEdges =
      (ws_size > fixed) ? (ws_size - fixed) / (kOut * sizeof(float)) : 0;
  int P = 64;
  for (int p = 1; p <= 64; ++p) {
    double epp = (double)kEdges / p;
    if (epp + 8.0 * sqrt(epp) + 16.0 <= (double)capEdges) {
      P = p;
      break;
    }
  }

  hipMemsetAsync(counts, 0, (size_t)kNodes * sizeof(int), stream);
  tables_kernel<<<(kGraphs * kOut + 255) / 256, 256, 0, stream>>>(
      u, W1, b1, W2, b2, U1, U2);
  pre_kernel<<<1024, 256, 0, stream>>>(x, W1, A1, A2);
  hist_kernel<<<2048, 256, 0, stream>>>(ei, counts);
  scan_reduce<<<NB, SB, 0, stream>>>(counts, bsum);
  scan_top<<<1, 512, 0, stream>>>(bsum);
  scan_final<<<NB, SB, 0, stream>>>(counts, bsum, offs, cursor);
  for (int q = 0; q < P; ++q) {
    int nlo = (int)((long long)q * kNodes / P);
    int nhi = (int)((long long)(q + 1) * kNodes / P);
    edge_msg_kernel<<<2048, 256, 0, stream>>>(ei, batch, ea, A1, A2, U1, W1,
                                              offs, cursor, msgbuf, nlo, nhi);
    sum_mlp2_kernel<<<1024, 256, 0, stream>>>(x, msgbuf, offs, batch, U2, W2,
                                              out, nlo, nhi);
  }
}

// Round 7
// 840.593 us; speedup vs baseline: 1.5936x; 1.4019x over previous
//
#include <hip/hip_runtime.h>

// GNN NodeModel, round 7: MFMA-tiled edge stage.
// R1/R3/R6 all hit ~650 us with ~12 VMEM instr/edge -> per-CU outstanding-
// VMEM (MLP) limit, independent of structure. R7 collapses it: 16 edges = one
// mfma_f32_16x16x32_bf16 tile; the A-fragment layout IS the gather (one
// dwordx4 per lane per K-slice = 0.25 instr/edge for the whole
// [x_d|x_s|ea|u_g] concat). Messages = relu(tile @ W1 + b1) in f32 acc,
// stored bf16 to dest-slot msgbuf (slots precomputed). Then streaming
// segment-sum + MLP2 (bf16 msgbuf read).
//
// math: msg_e = relu([x[d],x[s],ea_e,u[g]] @ W1 + b1)  (bf16 in, f32 acc)
//       agg[n] = sum msgbuf rows offs[n]..offs[n+1]
//       out = relu(x @ W2[0:32] + agg @ W2[32:96] + U2[batch]),
//       U2[g] = u[g] @ W2[96:128] + b2

constexpr int kNodes  = 100000;
constexpr int kEdges  = 1600000;
constexpr int kGraphs = 64;
constexpr int kD      = 32;
constexpr int kOut    = 64;
constexpr int kTiles  = kEdges / 16;  // 100000
constexpr int SB      = 256;
constexpr int NB      = (kNodes + SB - 1) / SB;  // 391
static_assert(kEdges % 16 == 0, "tile-exact");
static_assert(NB <= 512, "scan_top handles <=512 block sums");

using frag_b = __attribute__((ext_vector_type(8))) short;   // 8 bf16 = 4 VGPR
using f32x4  = __attribute__((ext_vector_type(4))) float;

__device__ __forceinline__ short f2bf(float f) {  // RNE f32 -> bf16
  unsigned u = __float_as_uint(f);
  return (short)((u + 0x7FFFu + ((u >> 16) & 1u)) >> 16);
}
__device__ __forceinline__ float bf2f(short h) {
  return __uint_as_float((unsigned)(unsigned short)h << 16);
}

// ---------------------------------------------------------------------------
__global__ __launch_bounds__(256) void cvt_kernel(const float* __restrict__ src,
                                                  short* __restrict__ dst,
                                                  int n4) {
  int i = blockIdx.x * 256 + threadIdx.x;
  int stride = gridDim.x * 256;
  for (; i < n4; i += stride) {
    float4 v = reinterpret_cast<const float4*>(src)[i];
    short4 h;
    h.x = f2bf(v.x); h.y = f2bf(v.y); h.z = f2bf(v.z); h.w = f2bf(v.w);
    reinterpret_cast<short4*>(dst)[i] = h;
  }
}

// W1 (128x64 f32, row-major) -> B-fragment order for 16x16x32 bf16:
// W1p[(ts*4+ntile)*64 + lane] = 8 bf16: k = ts*32 + (lane>>4)*8 + i,
// n = ntile*16 + (lane&15).
__global__ __launch_bounds__(256) void w1pack_kernel(
    const float* __restrict__ W1, uint4* __restrict__ W1p) {
  int idx = blockIdx.x * 256 + threadIdx.x;
  if (idx >= 1024) return;
  int lane = idx & 63, ntile = (idx >> 6) & 3, ts = idx >> 8;
  int n  = ntile * 16 + (lane & 15);
  int k0 = ts * 32 + ((lane >> 4) & 3) * 8;
  unsigned w[4];
#pragma unroll
  for (int p = 0; p < 4; ++p) {
    unsigned lo = (unsigned short)f2bf(W1[(size_t)(k0 + 2 * p) * kOut + n]);
    unsigned hi = (unsigned short)f2bf(W1[(size_t)(k0 + 2 * p + 1) * kOut + n]);
    w[p] = lo | (hi << 16);
  }
  W1p[idx] = make_uint4(w[0], w[1], w[2], w[3]);
}

// U2[g][j] = u[g] @ W2[96:128][:,j] + b2[j]
__global__ __launch_bounds__(256) void tables_kernel(
    const float* __restrict__ u, const float* __restrict__ W2,
    const float* __restrict__ b2, float* __restrict__ U2) {
  int t = blockIdx.x * 256 + threadIdx.x;
  if (t >= kGraphs * kOut) return;
  int g = t >> 6, j = t & 63;
  float a2 = b2[j];
#pragma unroll
  for (int k = 0; k < kD; ++k)
    a2 = fmaf(u[g * kD + k], W2[(size_t)(96 + k) * kOut + j], a2);
  U2[t] = a2;
}

// ---------------------------------------------------------------------------
__global__ __launch_bounds__(256) void hist_kernel(const int* __restrict__ ei,
                                                   int* __restrict__ counts) {
  int i = blockIdx.x * 256 + threadIdx.x;
  int stride = gridDim.x * 256;
  for (int e = i; e < kEdges; e += stride)
    atomicAdd(&counts[ei[kEdges + e]], 1);
}

__global__ __launch_bounds__(SB) void scan_reduce(const int* __restrict__ counts,
                                                  int* __restrict__ bsum) {
  __shared__ int s[SB];
  int i = blockIdx.x * SB + threadIdx.x;
  s[threadIdx.x] = (i < kNodes) ? counts[i] : 0;
  __syncthreads();
  for (int off = SB / 2; off > 0; off >>= 1) {
    if (threadIdx.x < off) s[threadIdx.x] += s[threadIdx.x + off];
    __syncthreads();
  }
  if (threadIdx.x == 0) bsum[blockIdx.x] = s[0];
}

__global__ __launch_bounds__(512) void scan_top(int* __restrict__ bsum) {
  __shared__ int s[512];
  int t = threadIdx.x;
  int orig = (t < NB) ? bsum[t] : 0;
  s[t] = orig;
  __syncthreads();
  for (int off = 1; off < 512; off <<= 1) {
    int a = (t >= off) ? s[t - off] : 0;
    __syncthreads();
    s[t] += a;
    __syncthreads();
  }
  if (t < NB) bsum[t] = s[t] - orig;  // exclusive
}

__global__ __launch_bounds__(SB) void scan_final(
    const int* __restrict__ counts, const int* __restrict__ bscan,
    int* __restrict__ offs, int* __restrict__ cursor) {
  __shared__ int s[SB];
  int i = blockIdx.x * SB + threadIdx.x;
  int v = (i < kNodes) ? counts[i] : 0;
  s[threadIdx.x] = v;
  __syncthreads();
  for (int off = 1; off < SB; off <<= 1) {
    int a = (threadIdx.x >= off) ? s[threadIdx.x - off] : 0;
    __syncthreads();
    s[threadIdx.x] += a;
    __syncthreads();
  }
  if (i < kNodes) {
    int ex = s[threadIdx.x] - v + bscan[blockIdx.x];
    offs[i] = ex;
    cursor[i] = ex;
  }
  if (blockIdx.x == 0 && threadIdx.x == 0) offs[kNodes] = kEdges;
}

// pos[e] = dest-sorted slot for edge e (order within a dest is arbitrary).
__global__ __launch_bounds__(256) void slot_kernel(const int* __restrict__ ei,
                                                   int* __restrict__ cursor,
                                                   int* __restrict__ pos) {
  int i = blockIdx.x * 256 + threadIdx.x;
  int stride = gridDim.x * 256;
  for (int e = i; e < kEdges; e += stride)
    pos[e] = atomicAdd(&cursor[ei[kEdges + e]], 1);
}

// ---------------------------------------------------------------------------
// One wave = grid-stride over 16-edge tiles. Per tile:
//   A (16x128 bf16) = [x_d | x_s | ea | u_g], one dwordx4 gather per lane per
//   K-slice (lane: edge-row = lane&15, k-quarter = lane>>4).
//   B = W1 fragments from LDS. 16 MFMA (4 N-tiles x 4 K-steps), f32 acc.
//   D: col = lane&15, row = (lane>>4)*4 + reg  [m89-verified layout].
//   Store: msgbuf[pos[row]*64 + ntile*16 + col] as bf16 (pos via one dwordx4:
//   pos[tb + (lane>>4)*4 + reg] == exactly this lane's 4 store rows).
__global__ __launch_bounds__(256) void edge_mfma_kernel(
    const int* __restrict__ ei, const int* __restrict__ batch,
    const short* __restrict__ xb, const short* __restrict__ eab,
    const short* __restrict__ ub, const uint4* __restrict__ W1p,
    const float* __restrict__ b1, const int* __restrict__ pos,
    short* __restrict__ msgbuf) {
  __shared__ uint4 sW[1024];  // 16 KB: [(ts*4+ntile)*64 + lane]
  for (int i = threadIdx.x; i < 1024; i += 256) sW[i] = W1p[i];
  __syncthreads();
  const int lane = threadIdx.x & 63;
  const int er   = lane & 15;  // A m-index (edge row); D n-col within ntile
  const int kq   = lane >> 4;  // k-quarter
  const int koff = kq * 8;
  float b1v[4];
#pragma unroll
  for (int n = 0; n < 4; ++n) b1v[n] = b1[n * 16 + er];
  const int wave = (blockIdx.x * 256 + threadIdx.x) >> 6;
  const int nw   = gridDim.x * 4;
  for (int t = wave; t < kTiles; t += nw) {
    const int tb = t * 16;
    const int s  = ei[tb + er];
    const int d  = ei[kEdges + tb + er];
    const int g  = batch[s];
    const uint4 pv = *reinterpret_cast<const uint4*>(pos + tb + kq * 4);
    frag_b a0 = *reinterpret_cast<const frag_b*>(xb + (size_t)d * kD + koff);
    frag_b a1 = *reinterpret_cast<const frag_b*>(xb + (size_t)s * kD + koff);
    frag_b a2 =
        *reinterpret_cast<const frag_b*>(eab + (size_t)(tb + er) * kD + koff);
    frag_b a3 = *reinterpret_cast<const frag_b*>(ub + g * kD + koff);
    f32x4 acc[4];
#pragma unroll
    for (int n = 0; n < 4; ++n) {
      acc[n] = (f32x4){0.f, 0.f, 0.f, 0.f};
      acc[n] = __builtin_amdgcn_mfma_f32_16x16x32_bf16(
          a0, *reinterpret_cast<const frag_b*>(&sW[(0 * 4 + n) * 64 + lane]),
          acc[n], 0, 0, 0);
      acc[n] = __builtin_amdgcn_mfma_f32_16x16x32_bf16(
          a1, *reinterpret_cast<const frag_b*>(&sW[(1 * 4 + n) * 64 + lane]),
          acc[n], 0, 0, 0);
      acc[n] = __builtin_amdgcn_mfma_f32_16x16x32_bf16(
          a2, *reinterpret_cast<const frag_b*>(&sW[(2 * 4 + n) * 64 + lane]),
          acc[n], 0, 0, 0);
      acc[n] = __builtin_amdgcn_mfma_f32_16x16x32_bf16(
          a3, *reinterpret_cast<const frag_b*>(&sW[(3 * 4 + n) * 64 + lane]),
          acc[n], 0, 0, 0);
    }
    const int prow[4] = {(int)pv.x, (int)pv.y, (int)pv.z, (int)pv.w};
#pragma unroll
    for (int n = 0; n < 4; ++n)
#pragma unroll
      for (int r = 0; r < 4; ++r) {
        float v = fmaxf(acc[n][r] + b1v[n], 0.f);
        msgbuf[(size_t)prow[r] * kOut + n * 16 + er] = f2bf(v);
      }
  }
}

// ---------------------------------------------------------------------------
// Per node: sum its contiguous bf16 msgbuf rows (f32 acc), then
// out = relu(x @ W2[0:32] + agg @ W2[32:96] + U2[batch]). One wave per node.
__global__ __launch_bounds__(256) void sum_mlp2_kernel(
    const float* __restrict__ x, const short* __restrict__ msgbuf,
    const int* __restrict__ offs, const int* __restrict__ batch,
    const float* __restrict__ U2, const float* __restrict__ W2,
    float* __restrict__ out) {
  __shared__ float sWa[kD * kOut];    // W2 rows 0..31  (x block)
  __shared__ float sWb[kOut * kOut];  // W2 rows 32..95 (agg block)
  __shared__ float aggrow[4 * kOut];
  for (int i = threadIdx.x; i < kD * kOut; i += 256) sWa[i] = W2[i];
  for (int i = threadIdx.x; i < kOut * kOut; i += 256)
    sWb[i] = W2[kD * kOut + i];
  __syncthreads();
  const int lane = threadIdx.x & 63;
  const int wv   = threadIdx.x >> 6;
  const int wave = (blockIdx.x * 256 + threadIdx.x) >> 6;
  const int nw   = gridDim.x * 4;
  for (int n = wave; n < kNodes; n += nw) {
    const int rb = offs[n], re = offs[n + 1];
    float a0 = 0.f, a1 = 0.f;
    int r = rb;
    for (; r + 1 < re; r += 2) {
      a0 += bf2f(msgbuf[(size_t)r * kOut + lane]);
      a1 += bf2f(msgbuf[(size_t)(r + 1) * kOut + lane]);
    }
    if (r < re) a0 += bf2f(msgbuf[(size_t)r * kOut + lane]);
    aggrow[wv * kOut + lane] = a0 + a1;
    float acc = U2[batch[n] * kOut + lane];
    const float4* xr = reinterpret_cast<const float4*>(x + (size_t)n * kD);
#pragma unroll
    for (int q = 0; q < 8; ++q) {
      float4 v = xr[q];
      int k = q * 4;
      acc = fmaf(v.x, sWa[(k + 0) * kOut + lane], acc);
      acc = fmaf(v.y, sWa[(k + 1) * kOut + lane], acc);
      acc = fmaf(v.z, sWa[(k + 2) * kOut + lane], acc);
      acc = fmaf(v.w, sWa[(k + 3) * kOut + lane], acc);
    }
#pragma unroll
    for (int q = 0; q < 16; ++q) {
      float4 v = *reinterpret_cast<const float4*>(&aggrow[wv * kOut + q * 4]);
      int k = q * 4;
      acc = fmaf(v.x, sWb[(k + 0) * kOut + lane], acc);
      acc = fmaf(v.y, sWb[(k + 1) * kOut + lane], acc);
      acc = fmaf(v.z, sWb[(k + 2) * kOut + lane], acc);
      acc = fmaf(v.w, sWb[(k + 3) * kOut + lane], acc);
    }
    out[(size_t)n * kOut + lane] = fmaxf(acc, 0.f);
  }
}

// ---------------------------------------------------------------------------
extern "C" void kernel_launch(void* const* d_in, const int* in_sizes, int n_in,
                              void* d_out, int out_size, void* d_ws,
                              size_t ws_size, hipStream_t stream) {
  const float* x     = (const float*)d_in[0];
  const int*   ei    = (const int*)d_in[1];
  const float* ea    = (const float*)d_in[2];
  const float* u     = (const float*)d_in[3];
  const int*   batch = (const int*)d_in[4];
  const float* W1    = (const float*)d_in[5];
  const float* b1    = (const float*)d_in[6];
  const float* W2    = (const float*)d_in[7];
  const float* b2    = (const float*)d_in[8];
  float* out = (float*)d_out;

  // Workspace (~322 MB; R6 proved ws >= ~460 MB):
  uint4* W1p   = (uint4*)d_ws;                          // 16 KB (16B-aligned)
  float* U2    = (float*)(W1p + 1024);                  // 16 KB
  int*   counts= (int*)(U2 + kGraphs * kOut);           // 400 KB
  int*   offs  = counts + kNodes;                       // kNodes+1
  int*   cursor= offs + kNodes + 1;
  int*   bsum  = cursor + kNodes;                       // NB
  int*   pos   = bsum + 512;                            // 6.4 MB
  short* xb    = (short*)(pos + kEdges);                // 6.4 MB
  short* ub    = xb + (size_t)kNodes * kD;              // 4 KB
  short* eab   = ub + kGraphs * kD;                     // 102.4 MB
  short* msgbuf= eab + (size_t)kEdges * kD;             // 204.8 MB

  hipMemsetAsync(counts, 0, (size_t)kNodes * sizeof(int), stream);
  cvt_kernel<<<2048, 256, 0, stream>>>(ea, eab, kEdges * kD / 4);
  cvt_kernel<<<512, 256, 0, stream>>>(x, xb, kNodes * kD / 4);
  cvt_kernel<<<2, 256, 0, stream>>>(u, ub, kGraphs * kD / 4);
  w1pack_kernel<<<4, 256, 0, stream>>>(W1, W1p);
  tables_kernel<<<(kGraphs * kOut + 255) / 256, 256, 0, stream>>>(u, W2, b2,
                                                                  U2);
  hist_kernel<<<2048, 256, 0, stream>>>(ei, counts);
  scan_reduce<<<NB, SB, 0, stream>>>(counts, bsum);
  scan_top<<<1, 512, 0, stream>>>(bsum);
  scan_final<<<NB, SB, 0, stream>>>(counts, bsum, offs, cursor);
  slot_kernel<<<2048, 256, 0, stream>>>(ei, cursor, pos);
  edge_mfma_kernel<<<2048, 256, 0, stream>>>(ei, batch, xb, eab, ub, W1p, b1,
                                             pos, msgbuf);
  sum_mlp2_kernel<<<1024, 256, 0, stream>>>(x, msgbuf, offs, batch, U2, W2,
                                            out);
}

// Round 8
// 767.404 us; speedup vs baseline: 1.7455x; 1.0954x over previous
//
#include <hip/hip_runtime.h>

// GNN NodeModel, round 8.
// R7 (MFMA edge tiles) proved the ~650us wall was VMEM-instr issue: 208us,
// 2.7 TB/s. Remaining ~630us is outside edge_mfma: sum_mlp2's scalar 2B/lane
// msgbuf walk (~300us est), cvt_ea pass (~70us), hist/slot (~70us).
// R8: (1) sum_mlp2 eats 8 rows per dwordx4 (1KB/wave-instr) + shfl-tree
//     reduce; (2) cvt_ea fused into edge_mfma (f32 read + in-reg bf16 pack);
//     (3) bigger sum grid.
//
// math: msg_e = relu([x[d],x[s],ea_e,u[g]] @ W1 + b1)  (bf16 in, f32 acc)
//       agg[n] = sum msgbuf rows offs[n]..offs[n+1]
//       out = relu(x @ W2[0:32] + agg @ W2[32:96] + U2[batch]),
//       U2[g] = u[g] @ W2[96:128] + b2

constexpr int kNodes  = 100000;
constexpr int kEdges  = 1600000;
constexpr int kGraphs = 64;
constexpr int kD      = 32;
constexpr int kOut    = 64;
constexpr int kTiles  = kEdges / 16;  // 100000
constexpr int SB      = 256;
constexpr int NB      = (kNodes + SB - 1) / SB;  // 391
static_assert(kEdges % 16 == 0, "tile-exact");
static_assert(NB <= 512, "scan_top handles <=512 block sums");

using frag_b = __attribute__((ext_vector_type(8))) short;   // 8 bf16 = 4 VGPR
using f32x4  = __attribute__((ext_vector_type(4))) float;

__device__ __forceinline__ short f2bf(float f) {  // RNE f32 -> bf16
  unsigned u = __float_as_uint(f);
  return (short)((u + 0x7FFFu + ((u >> 16) & 1u)) >> 16);
}
__device__ __forceinline__ unsigned pk2bf(float lo, float hi) {
  return (unsigned)(unsigned short)f2bf(lo) |
         ((unsigned)(unsigned short)f2bf(hi) << 16);
}
__device__ __forceinline__ float bf2f(short h) {
  return __uint_as_float((unsigned)(unsigned short)h << 16);
}
__device__ __forceinline__ float bflo(unsigned w) {
  return __uint_as_float(w << 16);
}
__device__ __forceinline__ float bfhi(unsigned w) {
  return __uint_as_float(w & 0xFFFF0000u);
}

// ---------------------------------------------------------------------------
__global__ __launch_bounds__(256) void cvt_kernel(const float* __restrict__ src,
                                                  short* __restrict__ dst,
                                                  int n4) {
  int i = blockIdx.x * 256 + threadIdx.x;
  int stride = gridDim.x * 256;
  for (; i < n4; i += stride) {
    float4 v = reinterpret_cast<const float4*>(src)[i];
    short4 h;
    h.x = f2bf(v.x); h.y = f2bf(v.y); h.z = f2bf(v.z); h.w = f2bf(v.w);
    reinterpret_cast<short4*>(dst)[i] = h;
  }
}

// W1 (128x64 f32, row-major) -> B-fragment order for 16x16x32 bf16:
// W1p[(ts*4+ntile)*64 + lane] = 8 bf16: k = ts*32 + (lane>>4)*8 + i,
// n = ntile*16 + (lane&15).
__global__ __launch_bounds__(256) void w1pack_kernel(
    const float* __restrict__ W1, uint4* __restrict__ W1p) {
  int idx = blockIdx.x * 256 + threadIdx.x;
  if (idx >= 1024) return;
  int lane = idx & 63, ntile = (idx >> 6) & 3, ts = idx >> 8;
  int n  = ntile * 16 + (lane & 15);
  int k0 = ts * 32 + ((lane >> 4) & 3) * 8;
  unsigned w[4];
#pragma unroll
  for (int p = 0; p < 4; ++p)
    w[p] = pk2bf(W1[(size_t)(k0 + 2 * p) * kOut + n],
                 W1[(size_t)(k0 + 2 * p + 1) * kOut + n]);
  W1p[idx] = make_uint4(w[0], w[1], w[2], w[3]);
}

// U2[g][j] = u[g] @ W2[96:128][:,j] + b2[j]
__global__ __launch_bounds__(256) void tables_kernel(
    const float* __restrict__ u, const float* __restrict__ W2,
    const float* __restrict__ b2, float* __restrict__ U2) {
  int t = blockIdx.x * 256 + threadIdx.x;
  if (t >= kGraphs * kOut) return;
  int g = t >> 6, j = t & 63;
  float a2 = b2[j];
#pragma unroll
  for (int k = 0; k < kD; ++k)
    a2 = fmaf(u[g * kD + k], W2[(size_t)(96 + k) * kOut + j], a2);
  U2[t] = a2;
}

// ---------------------------------------------------------------------------
__global__ __launch_bounds__(256) void hist_kernel(const int* __restrict__ ei,
                                                   int* __restrict__ counts) {
  int i = blockIdx.x * 256 + threadIdx.x;
  int stride = gridDim.x * 256;
  for (int e = i; e < kEdges; e += stride)
    atomicAdd(&counts[ei[kEdges + e]], 1);
}

__global__ __launch_bounds__(SB) void scan_reduce(const int* __restrict__ counts,
                                                  int* __restrict__ bsum) {
  __shared__ int s[SB];
  int i = blockIdx.x * SB + threadIdx.x;
  s[threadIdx.x] = (i < kNodes) ? counts[i] : 0;
  __syncthreads();
  for (int off = SB / 2; off > 0; off >>= 1) {
    if (threadIdx.x < off) s[threadIdx.x] += s[threadIdx.x + off];
    __syncthreads();
  }
  if (threadIdx.x == 0) bsum[blockIdx.x] = s[0];
}

__global__ __launch_bounds__(512) void scan_top(int* __restrict__ bsum) {
  __shared__ int s[512];
  int t = threadIdx.x;
  int orig = (t < NB) ? bsum[t] : 0;
  s[t] = orig;
  __syncthreads();
  for (int off = 1; off < 512; off <<= 1) {
    int a = (t >= off) ? s[t - off] : 0;
    __syncthreads();
    s[t] += a;
    __syncthreads();
  }
  if (t < NB) bsum[t] = s[t] - orig;  // exclusive
}

__global__ __launch_bounds__(SB) void scan_final(
    const int* __restrict__ counts, const int* __restrict__ bscan,
    int* __restrict__ offs, int* __restrict__ cursor) {
  __shared__ int s[SB];
  int i = blockIdx.x * SB + threadIdx.x;
  int v = (i < kNodes) ? counts[i] : 0;
  s[threadIdx.x] = v;
  __syncthreads();
  for (int off = 1; off < SB; off <<= 1) {
    int a = (threadIdx.x >= off) ? s[threadIdx.x - off] : 0;
    __syncthreads();
    s[threadIdx.x] += a;
    __syncthreads();
  }
  if (i < kNodes) {
    int ex = s[threadIdx.x] - v + bscan[blockIdx.x];
    offs[i] = ex;
    cursor[i] = ex;
  }
  if (blockIdx.x == 0 && threadIdx.x == 0) offs[kNodes] = kEdges;
}

// pos[e] = dest-sorted slot for edge e (order within a dest is arbitrary).
__global__ __launch_bounds__(256) void slot_kernel(const int* __restrict__ ei,
                                                   int* __restrict__ cursor,
                                                   int* __restrict__ pos) {
  int i = blockIdx.x * 256 + threadIdx.x;
  int stride = gridDim.x * 256;
  for (int e = i; e < kEdges; e += stride)
    pos[e] = atomicAdd(&cursor[ei[kEdges + e]], 1);
}

// ---------------------------------------------------------------------------
// One wave = grid-stride over 16-edge tiles. A (16x128 bf16) =
// [x_d | x_s | ea | u_g]: x/u from bf16 tables (one dwordx4 per lane), ea
// read f32 directly (2 dwordx4) and packed in-register. B = W1 frags in LDS.
// 16 MFMA, f32 acc. D layout: col=lane&15, row=(lane>>4)*4+reg (m89).
// Stores: bf16 to msgbuf[pos[row]*64 + n*16 + col].
__global__ __launch_bounds__(256) void edge_mfma_kernel(
    const int* __restrict__ ei, const int* __restrict__ batch,
    const short* __restrict__ xb, const float* __restrict__ ea,
    const short* __restrict__ ub, const uint4* __restrict__ W1p,
    const float* __restrict__ b1, const int* __restrict__ pos,
    short* __restrict__ msgbuf) {
  __shared__ uint4 sW[1024];  // 16 KB: [(ts*4+ntile)*64 + lane]
  for (int i = threadIdx.x; i < 1024; i += 256) sW[i] = W1p[i];
  __syncthreads();
  const int lane = threadIdx.x & 63;
  const int er   = lane & 15;  // A m-index (edge row); D n-col within ntile
  const int kq   = lane >> 4;  // k-quarter
  const int koff = kq * 8;
  float b1v[4];
#pragma unroll
  for (int n = 0; n < 4; ++n) b1v[n] = b1[n * 16 + er];
  const int wave = (blockIdx.x * 256 + threadIdx.x) >> 6;
  const int nw   = gridDim.x * 4;
  for (int t = wave; t < kTiles; t += nw) {
    const int tb = t * 16;
    const int s  = ei[tb + er];
    const int d  = ei[kEdges + tb + er];
    const int g  = batch[s];
    const uint4 pv = *reinterpret_cast<const uint4*>(pos + tb + kq * 4);
    frag_b a0 = *reinterpret_cast<const frag_b*>(xb + (size_t)d * kD + koff);
    frag_b a1 = *reinterpret_cast<const frag_b*>(xb + (size_t)s * kD + koff);
    const float4* ef =
        reinterpret_cast<const float4*>(ea + (size_t)(tb + er) * kD + koff);
    float4 e0 = ef[0], e1 = ef[1];
    frag_b a3 = *reinterpret_cast<const frag_b*>(ub + g * kD + koff);
    union { frag_b f; unsigned w[4]; } a2u;
    a2u.w[0] = pk2bf(e0.x, e0.y);
    a2u.w[1] = pk2bf(e0.z, e0.w);
    a2u.w[2] = pk2bf(e1.x, e1.y);
    a2u.w[3] = pk2bf(e1.z, e1.w);
    f32x4 acc[4];
#pragma unroll
    for (int n = 0; n < 4; ++n) {
      acc[n] = (f32x4){0.f, 0.f, 0.f, 0.f};
      acc[n] = __builtin_amdgcn_mfma_f32_16x16x32_bf16(
          a0, *reinterpret_cast<const frag_b*>(&sW[(0 * 4 + n) * 64 + lane]),
          acc[n], 0, 0, 0);
      acc[n] = __builtin_amdgcn_mfma_f32_16x16x32_bf16(
          a1, *reinterpret_cast<const frag_b*>(&sW[(1 * 4 + n) * 64 + lane]),
          acc[n], 0, 0, 0);
      acc[n] = __builtin_amdgcn_mfma_f32_16x16x32_bf16(
          a2u.f, *reinterpret_cast<const frag_b*>(&sW[(2 * 4 + n) * 64 + lane]),
          acc[n], 0, 0, 0);
      acc[n] = __builtin_amdgcn_mfma_f32_16x16x32_bf16(
          a3, *reinterpret_cast<const frag_b*>(&sW[(3 * 4 + n) * 64 + lane]),
          acc[n], 0, 0, 0);
    }
    const int prow[4] = {(int)pv.x, (int)pv.y, (int)pv.z, (int)pv.w};
#pragma unroll
    for (int n = 0; n < 4; ++n)
#pragma unroll
      for (int r = 0; r < 4; ++r) {
        float v = fmaxf(acc[n][r] + b1v[n], 0.f);
        msgbuf[(size_t)prow[r] * kOut + n * 16 + er] = f2bf(v);
      }
  }
}

// ---------------------------------------------------------------------------
// Per node: segment-sum bf16 msgbuf rows 8-rows-per-dwordx4 (lane holds cols
// (lane&7)*8..+8 of row rb+(lane>>3)), shfl_xor(8/16/32) tree reduce, tail
// rows scalar. Then out = relu(x @ W2[0:32] + agg @ W2[32:96] + U2[batch]).
__global__ __launch_bounds__(256) void sum_mlp2_kernel(
    const float* __restrict__ x, const short* __restrict__ msgbuf,
    const int* __restrict__ offs, const int* __restrict__ batch,
    const float* __restrict__ U2, const float* __restrict__ W2,
    float* __restrict__ out) {
  __shared__ float sWa[kD * kOut];    // W2 rows 0..31  (x block)
  __shared__ float sWb[kOut * kOut];  // W2 rows 32..95 (agg block)
  __shared__ float aggrow[4 * kOut];
  for (int i = threadIdx.x; i < kD * kOut; i += 256) sWa[i] = W2[i];
  for (int i = threadIdx.x; i < kOut * kOut; i += 256)
    sWb[i] = W2[kD * kOut + i];
  __syncthreads();
  const int lane = threadIdx.x & 63;
  const int wv   = threadIdx.x >> 6;
  const int wave = (blockIdx.x * 256 + threadIdx.x) >> 6;
  const int nw   = gridDim.x * 4;
  const int c0   = (lane & 7) * 8;  // vector-path col base for this lane
  for (int n = wave; n < kNodes; n += nw) {
    const int rb = offs[n], re = offs[n + 1];
    float vs[8];
#pragma unroll
    for (int j = 0; j < 8; ++j) vs[j] = 0.f;
    int r = rb;
    for (; r + 8 <= re; r += 8) {
      // 64 lanes x 16B = rows r..r+7 (1 KB contiguous)
      uint4 w = reinterpret_cast<const uint4*>(msgbuf + (size_t)r * kOut)[lane];
      vs[0] += bflo(w.x); vs[1] += bfhi(w.x);
      vs[2] += bflo(w.y); vs[3] += bfhi(w.y);
      vs[4] += bflo(w.z); vs[5] += bfhi(w.z);
      vs[6] += bflo(w.w); vs[7] += bfhi(w.w);
    }
#pragma unroll
    for (int st = 8; st < 64; st <<= 1)
#pragma unroll
      for (int j = 0; j < 8; ++j) vs[j] += __shfl_xor(vs[j], st);
    // all lanes now hold full sums for cols c0..c0+7; write (redundant ok)
#pragma unroll
    for (int j = 0; j < 8; ++j) aggrow[wv * kOut + c0 + j] = vs[j];
    float tail = 0.f;
    for (; r < re; ++r) tail += bf2f(msgbuf[(size_t)r * kOut + lane]);
    aggrow[wv * kOut + lane] += tail;
    float acc = U2[batch[n] * kOut + lane];
    const float4* xr = reinterpret_cast<const float4*>(x + (size_t)n * kD);
#pragma unroll
    for (int q = 0; q < 8; ++q) {
      float4 v = xr[q];
      int k = q * 4;
      acc = fmaf(v.x, sWa[(k + 0) * kOut + lane], acc);
      acc = fmaf(v.y, sWa[(k + 1) * kOut + lane], acc);
      acc = fmaf(v.z, sWa[(k + 2) * kOut + lane], acc);
      acc = fmaf(v.w, sWa[(k + 3) * kOut + lane], acc);
    }
#pragma unroll
    for (int q = 0; q < 16; ++q) {
      float4 v = *reinterpret_cast<const float4*>(&aggrow[wv * kOut + q * 4]);
      int k = q * 4;
      acc = fmaf(v.x, sWb[(k + 0) * kOut + lane], acc);
      acc = fmaf(v.y, sWb[(k + 1) * kOut + lane], acc);
      acc = fmaf(v.z, sWb[(k + 2) * kOut + lane], acc);
      acc = fmaf(v.w, sWb[(k + 3) * kOut + lane], acc);
    }
    out[(size_t)n * kOut + lane] = fmaxf(acc, 0.f);
  }
}

// ---------------------------------------------------------------------------
extern "C" void kernel_launch(void* const* d_in, const int* in_sizes, int n_in,
                              void* d_out, int out_size, void* d_ws,
                              size_t ws_size, hipStream_t stream) {
  const float* x     = (const float*)d_in[0];
  const int*   ei    = (const int*)d_in[1];
  const float* ea    = (const float*)d_in[2];
  const float* u     = (const float*)d_in[3];
  const int*   batch = (const int*)d_in[4];
  const float* W1    = (const float*)d_in[5];
  const float* b1    = (const float*)d_in[6];
  const float* W2    = (const float*)d_in[7];
  const float* b2    = (const float*)d_in[8];
  float* out = (float*)d_out;

  // Workspace (~219 MB; 256B-aligned blocks).
  auto align256 = [](char* p) {
    return (char*)(((size_t)p + 255) & ~(size_t)255);
  };
  char* p = (char*)d_ws;
  uint4* W1p = (uint4*)p;                 p = align256(p + 1024 * 16);
  float* U2  = (float*)p;                 p = align256(p + kGraphs * kOut * 4);
  int* counts = (int*)p;                  p = align256(p + kNodes * 4);
  int* offs   = (int*)p;                  p = align256(p + (kNodes + 1) * 4);
  int* cursor = (int*)p;                  p = align256(p + kNodes * 4);
  int* bsum   = (int*)p;                  p = align256(p + 512 * 4);
  int* pos    = (int*)p;                  p = align256(p + (size_t)kEdges * 4);
  short* xb   = (short*)p;                p = align256(p + (size_t)kNodes * kD * 2);
  short* ub   = (short*)p;                p = align256(p + kGraphs * kD * 2);
  short* msgbuf = (short*)p;              // kEdges*kOut*2 = 204.8 MB

  hipMemsetAsync(counts, 0, (size_t)kNodes * sizeof(int), stream);
  cvt_kernel<<<512, 256, 0, stream>>>(x, xb, kNodes * kD / 4);
  cvt_kernel<<<2, 256, 0, stream>>>(u, ub, kGraphs * kD / 4);
  w1pack_kernel<<<4, 256, 0, stream>>>(W1, W1p);
  tables_kernel<<<(kGraphs * kOut + 255) / 256, 256, 0, stream>>>(u, W2, b2,
                                                                  U2);
  hist_kernel<<<2048, 256, 0, stream>>>(ei, counts);
  scan_reduce<<<NB, SB, 0, stream>>>(counts, bsum);
  scan_top<<<1, 512, 0, stream>>>(bsum);
  scan_final<<<NB, SB, 0, stream>>>(counts, bsum, offs, cursor);
  slot_kernel<<<2048, 256, 0, stream>>>(ei, cursor, pos);
  edge_mfma_kernel<<<2048, 256, 0, stream>>>(ei, batch, xb, ea, ub, W1p, b1,
                                             pos, msgbuf);
  sum_mlp2_kernel<<<2048, 256, 0, stream>>>(x, msgbuf, offs, batch, U2, W2,
                                            out);
}

// Round 10
// 747.949 us; speedup vs baseline: 1.7909x; 1.0260x over previous
//
#include <hip/hip_runtime.h>

// GNN NodeModel, round 9 resubmit (R9 bench was GPUAcquisitionTimeout; no data).
// R7 proved MFMA-tiling kills the VMEM-issue wall (650->208us).
// R8's remaining costs: sum_mlp2 latency-bound per-node tree (204us), msgbuf
// round-trip (450MB), ~360us of fixed passes/launch gaps.
// R9: edge kernel walks SLOTS (dest-sorted) -> stores die entirely; messages
// transposed through per-wave swizzled LDS, segment-summed with wave-uniform
// flushes into block LDS acc (block owns 64 aligned nodes), plain agg stores.
// slot_kernel packs {e,dl | s,g} per slot -> one coalesced 8B load replaces
// the inv->ei->batch chain. msgbuf deleted; ws ~47MB. 8 launches + memset.
//
// math: msg_e = relu([x[d],x[s],ea_e,u[g]] @ W1 + b1)  (bf16 in, f32 acc)
//       agg[n] = sum of msg over slots offs[n]..offs[n+1]
//       out = relu(x @ W2[0:32] + agg @ W2[32:96] + U2[batch]),
//       U2[g] = u[g] @ W2[96:128] + b2

constexpr int kNodes  = 100000;
constexpr int kEdges  = 1600000;
constexpr int kGraphs = 64;
constexpr int kD      = 32;
constexpr int kOut    = 64;
constexpr int SB      = 256;
constexpr int NB      = (kNodes + SB - 1) / SB;  // 391
constexpr int NPB     = 64;                      // nodes per agg block
constexpr int NAB     = (kNodes + NPB - 1) / NPB;  // 1563
static_assert(kEdges % 16 == 0, "tile-exact");
static_assert(NB <= 512, "scan_top handles <=512 block sums");

using frag_b = __attribute__((ext_vector_type(8))) short;   // 8 bf16 = 4 VGPR
using f32x4  = __attribute__((ext_vector_type(4))) float;

__device__ __forceinline__ short f2bf(float f) {  // RNE f32 -> bf16
  unsigned u = __float_as_uint(f);
  return (short)((u + 0x7FFFu + ((u >> 16) & 1u)) >> 16);
}
__device__ __forceinline__ unsigned pk2bf(float lo, float hi) {
  return (unsigned)(unsigned short)f2bf(lo) |
         ((unsigned)(unsigned short)f2bf(hi) << 16);
}

// ---------------------------------------------------------------------------
// prep: [0,512) cvt x->bf16; 512 cvt u; [513,517) pack W1; [517,533) U2 table.
__global__ __launch_bounds__(256) void prep_kernel(
    const float* __restrict__ x, const float* __restrict__ u,
    const float* __restrict__ W1, const float* __restrict__ W2,
    const float* __restrict__ b2, short* __restrict__ xb,
    short* __restrict__ ub, uint4* __restrict__ W1p, float* __restrict__ U2) {
  const int bid = blockIdx.x, tid = threadIdx.x;
  if (bid < 512) {
    const int n4 = kNodes * kD / 4;
    for (int i = bid * 256 + tid; i < n4; i += 512 * 256) {
      float4 v = reinterpret_cast<const float4*>(x)[i];
      short4 h;
      h.x = f2bf(v.x); h.y = f2bf(v.y); h.z = f2bf(v.z); h.w = f2bf(v.w);
      reinterpret_cast<short4*>(xb)[i] = h;
    }
  } else if (bid == 512) {
    for (int i = tid; i < kGraphs * kD / 4; i += 256) {
      float4 v = reinterpret_cast<const float4*>(u)[i];
      short4 h;
      h.x = f2bf(v.x); h.y = f2bf(v.y); h.z = f2bf(v.z); h.w = f2bf(v.w);
      reinterpret_cast<short4*>(ub)[i] = h;
    }
  } else if (bid < 517) {
    int idx = (bid - 513) * 256 + tid;
    if (idx < 1024) {
      int lane = idx & 63, ntile = (idx >> 6) & 3, ts = idx >> 8;
      int n  = ntile * 16 + (lane & 15);
      int k0 = ts * 32 + ((lane >> 4) & 3) * 8;
      unsigned w[4];
#pragma unroll
      for (int p = 0; p < 4; ++p)
        w[p] = pk2bf(W1[(size_t)(k0 + 2 * p) * kOut + n],
                     W1[(size_t)(k0 + 2 * p + 1) * kOut + n]);
      W1p[idx] = make_uint4(w[0], w[1], w[2], w[3]);
    }
  } else {
    int t = (bid - 517) * 256 + tid;
    if (t < kGraphs * kOut) {
      int g = t >> 6, j = t & 63;
      float a2 = b2[j];
#pragma unroll
      for (int k = 0; k < kD; ++k)
        a2 = fmaf(u[g * kD + k], W2[(size_t)(96 + k) * kOut + j], a2);
      U2[t] = a2;
    }
  }
}

// ---------------------------------------------------------------------------
__global__ __launch_bounds__(256) void hist_kernel(const int* __restrict__ ei,
                                                   int* __restrict__ counts) {
  int i = blockIdx.x * 256 + threadIdx.x;
  int stride = gridDim.x * 256;
  for (int e = i; e < kEdges; e += stride)
    atomicAdd(&counts[ei[kEdges + e]], 1);
}

__global__ __launch_bounds__(SB) void scan_reduce(const int* __restrict__ counts,
                                                  int* __restrict__ bsum) {
  __shared__ int s[SB];
  int i = blockIdx.x * SB + threadIdx.x;
  s[threadIdx.x] = (i < kNodes) ? counts[i] : 0;
  __syncthreads();
  for (int off = SB / 2; off > 0; off >>= 1) {
    if (threadIdx.x < off) s[threadIdx.x] += s[threadIdx.x + off];
    __syncthreads();
  }
  if (threadIdx.x == 0) bsum[blockIdx.x] = s[0];
}

__global__ __launch_bounds__(512) void scan_top(int* __restrict__ bsum) {
  __shared__ int s[512];
  int t = threadIdx.x;
  int orig = (t < NB) ? bsum[t] : 0;
  s[t] = orig;
  __syncthreads();
  for (int off = 1; off < 512; off <<= 1) {
    int a = (t >= off) ? s[t - off] : 0;
    __syncthreads();
    s[t] += a;
    __syncthreads();
  }
  if (t < NB) bsum[t] = s[t] - orig;  // exclusive
}

__global__ __launch_bounds__(SB) void scan_final(
    const int* __restrict__ counts, const int* __restrict__ bscan,
    int* __restrict__ offs, int* __restrict__ cursor) {
  __shared__ int s[SB];
  int i = blockIdx.x * SB + threadIdx.x;
  int v = (i < kNodes) ? counts[i] : 0;
  s[threadIdx.x] = v;
  __syncthreads();
  for (int off = 1; off < SB; off <<= 1) {
    int a = (threadIdx.x >= off) ? s[threadIdx.x - off] : 0;
    __syncthreads();
    s[threadIdx.x] += a;
    __syncthreads();
  }
  if (i < kNodes) {
    int ex = s[threadIdx.x] - v + bscan[blockIdx.x];
    offs[i] = ex;
    cursor[i] = ex;
  }
  if (blockIdx.x == 0 && threadIdx.x == 0) offs[kNodes] = kEdges;
}

// urec[slot] = { e | (d&63)<<21 , s | g<<17 }  (e<2^21, s<2^17, g<64)
__global__ __launch_bounds__(256) void slot_kernel(
    const int* __restrict__ ei, const int* __restrict__ batch,
    int* __restrict__ cursor, uint2* __restrict__ urec) {
  int i = blockIdx.x * 256 + threadIdx.x;
  int stride = gridDim.x * 256;
  for (int e = i; e < kEdges; e += stride) {
    int s = ei[e];
    int d = ei[kEdges + e];
    int g = batch[s];
    int p = atomicAdd(&cursor[d], 1);
    urec[p] = make_uint2((unsigned)e | ((unsigned)(d & 63) << 21),
                         (unsigned)s | ((unsigned)g << 17));
  }
}

// ---------------------------------------------------------------------------
// Block owns nodes [n0, n0+NPB) and their dest-sorted slot range [beg,end).
// 4 waves process 16-slot tiles (ragged boundary tiles shared with neighbor
// blocks, rows masked at flush). Per tile: one coalesced urec load gives
// e/dl/s/g; A=[x_d|x_s|ea|u_g] gathered per lane (4x dwordx4-class loads);
// 16 MFMA vs LDS W1 frags; D -> per-wave swizzled LDS tile (bias+relu);
// 16-row walk accumulates col=lane with wave-uniform dl-segment flushes into
// block LDS sAcc (ds_add, conflict-free); final plain coalesced agg stores.
__global__ __launch_bounds__(256) void edge_agg_kernel(
    const uint2* __restrict__ urec, const int* __restrict__ offs,
    const short* __restrict__ xb, const float* __restrict__ ea,
    const short* __restrict__ ub, const uint4* __restrict__ W1p,
    const float* __restrict__ b1, float* __restrict__ agg) {
  __shared__ uint4 sW[1024];          // 16 KB
  __shared__ float sAcc[NPB * kOut];  // 16 KB
  __shared__ float msgT[4][16 * 64];  // 16 KB (4 KB per wave)
  const int tid  = threadIdx.x;
  const int lane = tid & 63;
  const int wv   = tid >> 6;
  const int er   = lane & 15;
  const int kq   = lane >> 4;
  const int koff = kq * 8;
  for (int i = tid; i < 1024; i += 256) sW[i] = W1p[i];
  for (int i = tid; i < NPB * kOut; i += 256) sAcc[i] = 0.f;
  __syncthreads();
  float b1v[4];
#pragma unroll
  for (int n = 0; n < 4; ++n) b1v[n] = b1[n * 16 + er];
  const int n0  = blockIdx.x * NPB;
  const int n1  = min(n0 + NPB, kNodes);
  const int beg = offs[n0], end = offs[n1];
  const int tb0 = (beg >> 4) << 4;  // floor to tile boundary
  for (int tb = tb0 + (wv << 4); tb < end; tb += 64) {
    const uint2 rc = urec[tb + er];  // 4-way broadcast per er
    const int e  = min((int)(rc.x & 0x1FFFFFu), kEdges - 1);
    const int dl = (int)((rc.x >> 21) & 63u);
    const int s  = min((int)(rc.y & 0x1FFFFu), kNodes - 1);
    const int g  = (int)(rc.y >> 17) & 63;
    const int d  = min(n0 + dl, kNodes - 1);
    frag_b a0 = *reinterpret_cast<const frag_b*>(xb + (size_t)d * kD + koff);
    frag_b a1 = *reinterpret_cast<const frag_b*>(xb + (size_t)s * kD + koff);
    const float4* ef =
        reinterpret_cast<const float4*>(ea + (size_t)e * kD + koff);
    float4 e0 = ef[0], e1 = ef[1];
    frag_b a3 = *reinterpret_cast<const frag_b*>(ub + g * kD + koff);
    union { frag_b f; unsigned w[4]; } a2u;
    a2u.w[0] = pk2bf(e0.x, e0.y);
    a2u.w[1] = pk2bf(e0.z, e0.w);
    a2u.w[2] = pk2bf(e1.x, e1.y);
    a2u.w[3] = pk2bf(e1.z, e1.w);
    f32x4 acc[4];
#pragma unroll
    for (int n = 0; n < 4; ++n) {
      acc[n] = (f32x4){0.f, 0.f, 0.f, 0.f};
      acc[n] = __builtin_amdgcn_mfma_f32_16x16x32_bf16(
          a0, *reinterpret_cast<const frag_b*>(&sW[(0 * 4 + n) * 64 + lane]),
          acc[n], 0, 0, 0);
      acc[n] = __builtin_amdgcn_mfma_f32_16x16x32_bf16(
          a1, *reinterpret_cast<const frag_b*>(&sW[(1 * 4 + n) * 64 + lane]),
          acc[n], 0, 0, 0);
      acc[n] = __builtin_amdgcn_mfma_f32_16x16x32_bf16(
          a2u.f, *reinterpret_cast<const frag_b*>(&sW[(2 * 4 + n) * 64 + lane]),
          acc[n], 0, 0, 0);
      acc[n] = __builtin_amdgcn_mfma_f32_16x16x32_bf16(
          a3, *reinterpret_cast<const frag_b*>(&sW[(3 * 4 + n) * 64 + lane]),
          acc[n], 0, 0, 0);
    }
    // D (col = n*16+er, row = kq*4+r) -> swizzled per-wave tile, bias+relu.
#pragma unroll
    for (int n = 0; n < 4; ++n) {
      const int c = n * 16 + er;
#pragma unroll
      for (int r = 0; r < 4; ++r) {
        const int row = kq * 4 + r;
        msgT[wv][row * 64 + ((c + row * 8) & 63)] =
            fmaxf(acc[n][r] + b1v[n], 0.f);
      }
    }
    // Segment-sum the 16 rows (col = lane), wave-uniform flushes.
    float al = 0.f;
    int dcur = -1;
#pragma unroll
    for (int r = 0; r < 16; ++r) {
      const int q = tb + r;
      if (q < beg || q >= end) continue;  // uniform mask (ragged tiles)
      const int dr = __shfl(dl, r);
      const float v = msgT[wv][r * 64 + ((lane + r * 8) & 63)];
      if (dr != dcur) {
        if (dcur >= 0) unsafeAtomicAdd(&sAcc[dcur * kOut + lane], al);
        al = 0.f;
        dcur = dr;
      }
      al += v;
    }
    if (dcur >= 0) unsafeAtomicAdd(&sAcc[dcur * kOut + lane], al);
  }
  __syncthreads();
  for (int r = wv; r < n1 - n0; r += 4)
    agg[(size_t)(n0 + r) * kOut + lane] = sAcc[r * kOut + lane];
}

// ---------------------------------------------------------------------------
// out = relu(x @ W2[0:32] + agg @ W2[32:96] + U2[batch]). One wave per node.
__global__ __launch_bounds__(256) void mlp2_kernel(
    const float* __restrict__ x, const float* __restrict__ agg,
    const int* __restrict__ batch, const float* __restrict__ U2,
    const float* __restrict__ W2, float* __restrict__ out) {
  __shared__ float sWa[kD * kOut];    // W2 rows 0..31  (x block)
  __shared__ float sWb[kOut * kOut];  // W2 rows 32..95 (agg block)
  for (int i = threadIdx.x; i < kD * kOut; i += 256) sWa[i] = W2[i];
  for (int i = threadIdx.x; i < kOut * kOut; i += 256)
    sWb[i] = W2[kD * kOut + i];
  __syncthreads();
  const int lane = threadIdx.x & 63;
  const int wave = (blockIdx.x * 256 + threadIdx.x) >> 6;
  const int nw   = gridDim.x * 4;
  for (int n = wave; n < kNodes; n += nw) {
    float acc = U2[batch[n] * kOut + lane];
    const float4* xr = reinterpret_cast<const float4*>(x + (size_t)n * kD);
#pragma unroll
    for (int q = 0; q < 8; ++q) {
      float4 v = xr[q];
      int k = q * 4;
      acc = fmaf(v.x, sWa[(k + 0) * kOut + lane], acc);
      acc = fmaf(v.y, sWa[(k + 1) * kOut + lane], acc);
      acc = fmaf(v.z, sWa[(k + 2) * kOut + lane], acc);
      acc = fmaf(v.w, sWa[(k + 3) * kOut + lane], acc);
    }
    const float4* ar = reinterpret_cast<const float4*>(agg + (size_t)n * kOut);
#pragma unroll
    for (int q = 0; q < 16; ++q) {
      float4 v = ar[q];
      int k = q * 4;
      acc = fmaf(v.x, sWb[(k + 0) * kOut + lane], acc);
      acc = fmaf(v.y, sWb[(k + 1) * kOut + lane], acc);
      acc = fmaf(v.z, sWb[(k + 2) * kOut + lane], acc);
      acc = fmaf(v.w, sWb[(k + 3) * kOut + lane], acc);
    }
    out[(size_t)n * kOut + lane] = fmaxf(acc, 0.f);
  }
}

// ---------------------------------------------------------------------------
extern "C" void kernel_launch(void* const* d_in, const int* in_sizes, int n_in,
                              void* d_out, int out_size, void* d_ws,
                              size_t ws_size, hipStream_t stream) {
  const float* x     = (const float*)d_in[0];
  const int*   ei    = (const int*)d_in[1];
  const float* ea    = (const float*)d_in[2];
  const float* u     = (const float*)d_in[3];
  const int*   batch = (const int*)d_in[4];
  const float* W1    = (const float*)d_in[5];
  const float* b1    = (const float*)d_in[6];
  const float* W2    = (const float*)d_in[7];
  const float* b2    = (const float*)d_in[8];
  float* out = (float*)d_out;

  // Workspace (~47 MB; 256B-aligned blocks).
  auto align256 = [](char* p) {
    return (char*)(((size_t)p + 255) & ~(size_t)255);
  };
  char* p = (char*)d_ws;
  uint4* W1p  = (uint4*)p;  p = align256(p + 1024 * 16);
  float* U2   = (float*)p;  p = align256(p + kGraphs * kOut * 4);
  int* counts = (int*)p;    p = align256(p + kNodes * 4);
  int* offs   = (int*)p;    p = align256(p + (kNodes + 1) * 4);
  int* cursor = (int*)p;    p = align256(p + kNodes * 4);
  int* bsum   = (int*)p;    p = align256(p + 512 * 4);
  short* xb   = (short*)p;  p = align256(p + (size_t)kNodes * kD * 2);
  short* ub   = (short*)p;  p = align256(p + kGraphs * kD * 2);
  uint2* urec = (uint2*)p;  p = align256(p + (size_t)(kEdges + 16) * 8);
  float* agg  = (float*)p;  // kNodes*kOut*4 = 25.6 MB

  hipMemsetAsync(counts, 0, (size_t)kNodes * sizeof(int), stream);
  prep_kernel<<<533, 256, 0, stream>>>(x, u, W1, W2, b2, xb, ub, W1p, U2);
  hist_kernel<<<2048, 256, 0, stream>>>(ei, counts);
  scan_reduce<<<NB, SB, 0, stream>>>(counts, bsum);
  scan_top<<<1, 512, 0, stream>>>(bsum);
  scan_final<<<NB, SB, 0, stream>>>(counts, bsum, offs, cursor);
  slot_kernel<<<2048, 256, 0, stream>>>(ei, batch, cursor, urec);
  edge_agg_kernel<<<NAB, 256, 0, stream>>>(urec, offs, xb, ea, ub, W1p, b1,
                                           agg);
  mlp2_kernel<<<2048, 256, 0, stream>>>(x, agg, batch, U2, W2, out);
}